// Round 1
// baseline (44.758 us; speedup 1.0000x reference)
//
#include <hip/hip_runtime.h>

// velocity = MLP(concat[zone_embedding, person_attrs, time_vec])
// GCN layers in the reference are dead code (outputs unused) -> skipped.
//
// Shapes: N=100000 zones, emb=32, pa=8, tv=16 -> combined 56
//   h1 = relu(combined @ Wd1[56,64] + bd1)
//   h2 = relu(h1 @ Wd2[64,32] + bd2)
//   out = h2 @ Wd3[32,32] + bd3
//
// person+time part of combined is zone-uniform -> folded into h1_base once
// per block. Weights staged in LDS (uniform broadcast reads in inner loops).

#define BLK 128

__global__ __launch_bounds__(BLK) void zone_velocity_kernel(
    const float* __restrict__ t,
    const float* __restrict__ emb,      // [N,32]
    const float* __restrict__ pa,       // [8]
    const float* __restrict__ Wt1,      // [1,16]
    const float* __restrict__ bt1,      // [16]
    const float* __restrict__ Wt2,      // [16,16]
    const float* __restrict__ bt2,      // [16]
    const float* __restrict__ Wd1,      // [56,64]
    const float* __restrict__ bd1,      // [64]
    const float* __restrict__ Wd2,      // [64,32]
    const float* __restrict__ bd2,      // [32]
    const float* __restrict__ Wd3,      // [32,32]
    const float* __restrict__ bd3,      // [32]
    float* __restrict__ out,            // [N,32]
    int N)
{
    __shared__ float s_u[16];        // relu(t*Wt1+bt1)
    __shared__ float s_tv[16];       // time_vec
    __shared__ float s_h1b[64];      // bd1 + (person|time) @ Wd1[32:56]
    __shared__ float s_Wd1[32 * 64]; // rows 0..31 only (embedding part)
    __shared__ float s_Wd2[64 * 32];
    __shared__ float s_Wd3[32 * 32];
    __shared__ float s_bd2[32];
    __shared__ float s_bd3[32];

    const int tidx = threadIdx.x;

    // ---- stage weights into LDS (cooperative) ----
    for (int idx = tidx; idx < 32 * 64; idx += BLK) s_Wd1[idx] = Wd1[idx];
    for (int idx = tidx; idx < 64 * 32; idx += BLK) s_Wd2[idx] = Wd2[idx];
    for (int idx = tidx; idx < 32 * 32; idx += BLK) s_Wd3[idx] = Wd3[idx];
    if (tidx < 32) { s_bd2[tidx] = bd2[tidx]; s_bd3[tidx] = bd3[tidx]; }

    // ---- time encoder (tiny; 16 lanes) ----
    const float tval = t[0];
    if (tidx < 16) s_u[tidx] = fmaxf(tval * Wt1[tidx] + bt1[tidx], 0.0f);
    __syncthreads();
    if (tidx < 16) {
        float acc = bt2[tidx];
        #pragma unroll
        for (int k = 0; k < 16; k++) acc = fmaf(s_u[k], Wt2[k * 16 + tidx], acc);
        s_tv[tidx] = acc;  // no relu on second time layer
    }
    __syncthreads();

    // ---- h1 base: bd1 + person/time contributions (zone-uniform) ----
    if (tidx < 64) {
        float acc = bd1[tidx];
        #pragma unroll
        for (int k = 0; k < 8; k++)
            acc = fmaf(pa[k], Wd1[(32 + k) * 64 + tidx], acc);
        #pragma unroll
        for (int k = 0; k < 16; k++)
            acc = fmaf(s_tv[k], Wd1[(40 + k) * 64 + tidx], acc);
        s_h1b[tidx] = acc;
    }
    __syncthreads();

    const int i = blockIdx.x * BLK + tidx;
    if (i >= N) return;

    // ---- load this zone's embedding (vectorized) ----
    float e[32];
    const float4* e4 = reinterpret_cast<const float4*>(emb + (size_t)i * 32);
    #pragma unroll
    for (int q = 0; q < 8; q++) {
        float4 v = e4[q];
        e[4 * q + 0] = v.x; e[4 * q + 1] = v.y;
        e[4 * q + 2] = v.z; e[4 * q + 3] = v.w;
    }

    // ---- layer 1: h1[64] = relu(h1b + e @ Wd1[0:32]) ----
    float h1[64];
    #pragma unroll
    for (int j = 0; j < 64; j++) h1[j] = s_h1b[j];
    #pragma unroll 4
    for (int k = 0; k < 32; k++) {
        const float c = e[k];
        #pragma unroll
        for (int j = 0; j < 64; j++)
            h1[j] = fmaf(c, s_Wd1[k * 64 + j], h1[j]);
    }
    #pragma unroll
    for (int j = 0; j < 64; j++) h1[j] = fmaxf(h1[j], 0.0f);

    // ---- layer 2: h2[32] = relu(h1 @ Wd2 + bd2) ----
    float h2[32];
    #pragma unroll
    for (int j = 0; j < 32; j++) h2[j] = s_bd2[j];
    #pragma unroll 4
    for (int k = 0; k < 64; k++) {
        const float c = h1[k];
        #pragma unroll
        for (int j = 0; j < 32; j++)
            h2[j] = fmaf(c, s_Wd2[k * 32 + j], h2[j]);
    }
    #pragma unroll
    for (int j = 0; j < 32; j++) h2[j] = fmaxf(h2[j], 0.0f);

    // ---- layer 3: out = h2 @ Wd3 + bd3 ----
    float o[32];
    #pragma unroll
    for (int j = 0; j < 32; j++) o[j] = s_bd3[j];
    #pragma unroll 4
    for (int k = 0; k < 32; k++) {
        const float c = h2[k];
        #pragma unroll
        for (int j = 0; j < 32; j++)
            o[j] = fmaf(c, s_Wd3[k * 32 + j], o[j]);
    }

    // ---- coalesced store ----
    float4* o4 = reinterpret_cast<float4*>(out + (size_t)i * 32);
    #pragma unroll
    for (int q = 0; q < 8; q++) {
        float4 v;
        v.x = o[4 * q + 0]; v.y = o[4 * q + 1];
        v.z = o[4 * q + 2]; v.w = o[4 * q + 3];
        o4[q] = v;
    }
}

extern "C" void kernel_launch(void* const* d_in, const int* in_sizes, int n_in,
                              void* d_out, int out_size, void* d_ws, size_t ws_size,
                              hipStream_t stream) {
    // setup_inputs() order:
    //  0 t, 1 zone_embedding, 2 zone_features, 3 person_attrs, 4 edge_index,
    //  5 W1, 6 b1, 7 W2, 8 b2, 9 Wt1, 10 bt1, 11 Wt2, 12 bt2,
    // 13 Wd1, 14 bd1, 15 Wd2, 16 bd2, 17 Wd3, 18 bd3
    const float* t   = (const float*)d_in[0];
    const float* emb = (const float*)d_in[1];
    const float* pa  = (const float*)d_in[3];
    const float* Wt1 = (const float*)d_in[9];
    const float* bt1 = (const float*)d_in[10];
    const float* Wt2 = (const float*)d_in[11];
    const float* bt2 = (const float*)d_in[12];
    const float* Wd1 = (const float*)d_in[13];
    const float* bd1 = (const float*)d_in[14];
    const float* Wd2 = (const float*)d_in[15];
    const float* bd2 = (const float*)d_in[16];
    const float* Wd3 = (const float*)d_in[17];
    const float* bd3 = (const float*)d_in[18];

    const int N = in_sizes[1] / 32;  // 100000
    float* out = (float*)d_out;

    const int blocks = (N + BLK - 1) / BLK;
    zone_velocity_kernel<<<blocks, BLK, 0, stream>>>(
        t, emb, pa, Wt1, bt1, Wt2, bt2,
        Wd1, bd1, Wd2, bd2, Wd3, bd3, out, N);
}

// Round 2
// 43.090 us; speedup vs baseline: 1.0387x; 1.0387x over previous
//
#include <hip/hip_runtime.h>

// velocity = MLP(concat[zone_embedding, person_attrs, time_vec])
// GCN layers in the reference are dead code (outputs unused) -> skipped.
//
// Round-2 change: weights are wave-uniform -> read via the SCALAR path
// (s_load / constant cache) instead of LDS. Round-1 profiling showed the
// kernel bound on the LDS issue pipe (one ds_read_b32 per FMA), with
// VALUBusy at 14%. Uniform constant-index reads from global let the
// compiler emit batched s_load_dwordx16 + v_fma with SGPR weight operand.
//
// person+time part of combined (24 of 56 inputs) is zone-uniform -> folded
// into h1_base once per block (tiny LDS: 96 floats).

#define BLK 256

__global__ __launch_bounds__(BLK) void zone_velocity_kernel(
    const float* __restrict__ t,
    const float* __restrict__ emb,      // [N,32]
    const float* __restrict__ pa,       // [8]
    const float* __restrict__ Wt1,      // [1,16]
    const float* __restrict__ bt1,      // [16]
    const float* __restrict__ Wt2,      // [16,16]
    const float* __restrict__ bt2,      // [16]
    const float* __restrict__ Wd1,      // [56,64]
    const float* __restrict__ bd1,      // [64]
    const float* __restrict__ Wd2,      // [64,32]
    const float* __restrict__ bd2,      // [32]
    const float* __restrict__ Wd3,      // [32,32]
    const float* __restrict__ bd3,      // [32]
    float* __restrict__ out,            // [N,32]
    int N)
{
    __shared__ float s_u[16];   // relu(t*Wt1+bt1)
    __shared__ float s_tv[16];  // time_vec
    __shared__ float s_h1b[64]; // bd1 + (person|time) @ Wd1[32:56]

    const int tidx = threadIdx.x;

    // ---- time encoder (tiny; 16 lanes) ----
    const float tval = t[0];
    if (tidx < 16) s_u[tidx] = fmaxf(tval * Wt1[tidx] + bt1[tidx], 0.0f);
    __syncthreads();
    if (tidx < 16) {
        float acc = bt2[tidx];
        #pragma unroll
        for (int k = 0; k < 16; k++) acc = fmaf(s_u[k], Wt2[k * 16 + tidx], acc);
        s_tv[tidx] = acc;  // no relu on second time layer
    }
    __syncthreads();

    // ---- h1 base: bd1 + person/time contributions (zone-uniform) ----
    if (tidx < 64) {
        float acc = bd1[tidx];
        #pragma unroll
        for (int k = 0; k < 8; k++)
            acc = fmaf(pa[k], Wd1[(32 + k) * 64 + tidx], acc);
        #pragma unroll
        for (int k = 0; k < 16; k++)
            acc = fmaf(s_tv[k], Wd1[(40 + k) * 64 + tidx], acc);
        s_h1b[tidx] = acc;
    }
    __syncthreads();

    const int i = blockIdx.x * BLK + tidx;
    if (i >= N) return;

    // ---- h1 base into registers (LDS read once, 64 floats) ----
    float h1[64];
    #pragma unroll
    for (int j = 0; j < 64; j++) h1[j] = s_h1b[j];

    // ---- load this zone's embedding (vectorized, coalesced) ----
    float e[32];
    const float4* e4 = reinterpret_cast<const float4*>(emb + (size_t)i * 32);
    #pragma unroll
    for (int q = 0; q < 8; q++) {
        float4 v = e4[q];
        e[4 * q + 0] = v.x; e[4 * q + 1] = v.y;
        e[4 * q + 2] = v.z; e[4 * q + 3] = v.w;
    }

    // ---- layer 1: h1[64] += e @ Wd1[0:32]; relu ----
    // Wd1[k*64+j] is wave-uniform -> scalar loads, FMA with SGPR operand.
    #pragma unroll 4
    for (int k = 0; k < 32; k++) {
        const float c = e[k];
        #pragma unroll
        for (int j = 0; j < 64; j++)
            h1[j] = fmaf(c, Wd1[k * 64 + j], h1[j]);
    }
    #pragma unroll
    for (int j = 0; j < 64; j++) h1[j] = fmaxf(h1[j], 0.0f);

    // ---- layer 2: h2[32] = relu(h1 @ Wd2 + bd2) ----
    float h2[32];
    #pragma unroll
    for (int j = 0; j < 32; j++) h2[j] = bd2[j];
    #pragma unroll 4
    for (int k = 0; k < 64; k++) {
        const float c = h1[k];
        #pragma unroll
        for (int j = 0; j < 32; j++)
            h2[j] = fmaf(c, Wd2[k * 32 + j], h2[j]);
    }
    #pragma unroll
    for (int j = 0; j < 32; j++) h2[j] = fmaxf(h2[j], 0.0f);

    // ---- layer 3: out = h2 @ Wd3 + bd3 ----
    float o[32];
    #pragma unroll
    for (int j = 0; j < 32; j++) o[j] = bd3[j];
    #pragma unroll 4
    for (int k = 0; k < 32; k++) {
        const float c = h2[k];
        #pragma unroll
        for (int j = 0; j < 32; j++)
            o[j] = fmaf(c, Wd3[k * 32 + j], o[j]);
    }

    // ---- coalesced store ----
    float4* o4 = reinterpret_cast<float4*>(out + (size_t)i * 32);
    #pragma unroll
    for (int q = 0; q < 8; q++) {
        float4 v;
        v.x = o[4 * q + 0]; v.y = o[4 * q + 1];
        v.z = o[4 * q + 2]; v.w = o[4 * q + 3];
        o4[q] = v;
    }
}

extern "C" void kernel_launch(void* const* d_in, const int* in_sizes, int n_in,
                              void* d_out, int out_size, void* d_ws, size_t ws_size,
                              hipStream_t stream) {
    // setup_inputs() order:
    //  0 t, 1 zone_embedding, 2 zone_features, 3 person_attrs, 4 edge_index,
    //  5 W1, 6 b1, 7 W2, 8 b2, 9 Wt1, 10 bt1, 11 Wt2, 12 bt2,
    // 13 Wd1, 14 bd1, 15 Wd2, 16 bd2, 17 Wd3, 18 bd3
    const float* t   = (const float*)d_in[0];
    const float* emb = (const float*)d_in[1];
    const float* pa  = (const float*)d_in[3];
    const float* Wt1 = (const float*)d_in[9];
    const float* bt1 = (const float*)d_in[10];
    const float* Wt2 = (const float*)d_in[11];
    const float* bt2 = (const float*)d_in[12];
    const float* Wd1 = (const float*)d_in[13];
    const float* bd1 = (const float*)d_in[14];
    const float* Wd2 = (const float*)d_in[15];
    const float* bd2 = (const float*)d_in[16];
    const float* Wd3 = (const float*)d_in[17];
    const float* bd3 = (const float*)d_in[18];

    const int N = in_sizes[1] / 32;  // 100000
    float* out = (float*)d_out;

    const int blocks = (N + BLK - 1) / BLK;
    zone_velocity_kernel<<<blocks, BLK, 0, stream>>>(
        t, emb, pa, Wt1, bt1, Wt2, bt2,
        Wd1, bd1, Wd2, bd2, Wd3, bd3, out, N);
}

// Round 3
// 35.356 us; speedup vs baseline: 1.2659x; 1.2187x over previous
//
#include <hip/hip_runtime.h>

// velocity = MLP(concat[zone_embedding, person_attrs, time_vec])
// GCN layers in the reference are dead code (outputs unused) -> skipped.
//
// Round-3 change: FULL unroll of all k-loops. Round-2's `#pragma unroll 4`
// left k runtime -> e[k]/h1[k]/h2[k] runtime-indexed -> scratch allocation
// (VGPR_Count=52 < 96 needed; WRITE_SIZE 62MB vs 12.8MB ideal = spill
// traffic). Full unroll makes every array index compile-time -> registers.
// Weights stay on the scalar path (wave-uniform s_load -> SGPR fmac operand).

#define BLK 256

__global__ __launch_bounds__(BLK) void zone_velocity_kernel(
    const float* __restrict__ t,
    const float* __restrict__ emb,      // [N,32]
    const float* __restrict__ pa,       // [8]
    const float* __restrict__ Wt1,      // [1,16]
    const float* __restrict__ bt1,      // [16]
    const float* __restrict__ Wt2,      // [16,16]
    const float* __restrict__ bt2,      // [16]
    const float* __restrict__ Wd1,      // [56,64]
    const float* __restrict__ bd1,      // [64]
    const float* __restrict__ Wd2,      // [64,32]
    const float* __restrict__ bd2,      // [32]
    const float* __restrict__ Wd3,      // [32,32]
    const float* __restrict__ bd3,      // [32]
    float* __restrict__ out,            // [N,32]
    int N)
{
    __shared__ float s_u[16];   // relu(t*Wt1+bt1)
    __shared__ float s_tv[16];  // time_vec
    __shared__ float s_h1b[64]; // bd1 + (person|time) @ Wd1[32:56]

    const int tidx = threadIdx.x;

    // ---- time encoder (tiny; 16 lanes) ----
    const float tval = t[0];
    if (tidx < 16) s_u[tidx] = fmaxf(tval * Wt1[tidx] + bt1[tidx], 0.0f);
    __syncthreads();
    if (tidx < 16) {
        float acc = bt2[tidx];
        #pragma unroll
        for (int k = 0; k < 16; k++) acc = fmaf(s_u[k], Wt2[k * 16 + tidx], acc);
        s_tv[tidx] = acc;  // no relu on second time layer
    }
    __syncthreads();

    // ---- h1 base: bd1 + person/time contributions (zone-uniform) ----
    if (tidx < 64) {
        float acc = bd1[tidx];
        #pragma unroll
        for (int k = 0; k < 8; k++)
            acc = fmaf(pa[k], Wd1[(32 + k) * 64 + tidx], acc);
        #pragma unroll
        for (int k = 0; k < 16; k++)
            acc = fmaf(s_tv[k], Wd1[(40 + k) * 64 + tidx], acc);
        s_h1b[tidx] = acc;
    }
    __syncthreads();

    const int i = blockIdx.x * BLK + tidx;
    if (i >= N) return;

    // ---- h1 base into registers (broadcast LDS reads) ----
    float h1[64];
    #pragma unroll
    for (int j = 0; j < 64; j++) h1[j] = s_h1b[j];

    // ---- load this zone's embedding (vectorized, coalesced) ----
    float e[32];
    const float4* e4 = reinterpret_cast<const float4*>(emb + (size_t)i * 32);
    #pragma unroll
    for (int q = 0; q < 8; q++) {
        float4 v = e4[q];
        e[4 * q + 0] = v.x; e[4 * q + 1] = v.y;
        e[4 * q + 2] = v.z; e[4 * q + 3] = v.w;
    }

    // ---- layer 1: h1[64] += e @ Wd1[0:32]; relu ----
    // FULL unroll: constant indices -> e/h1 in VGPRs, Wd1 via s_load/SGPR.
    #pragma unroll
    for (int k = 0; k < 32; k++) {
        const float c = e[k];
        #pragma unroll
        for (int j = 0; j < 64; j++)
            h1[j] = fmaf(c, Wd1[k * 64 + j], h1[j]);
    }
    #pragma unroll
    for (int j = 0; j < 64; j++) h1[j] = fmaxf(h1[j], 0.0f);

    // ---- layer 2: h2[32] = relu(h1 @ Wd2 + bd2) ----
    float h2[32];
    #pragma unroll
    for (int j = 0; j < 32; j++) h2[j] = bd2[j];
    #pragma unroll
    for (int k = 0; k < 64; k++) {
        const float c = h1[k];
        #pragma unroll
        for (int j = 0; j < 32; j++)
            h2[j] = fmaf(c, Wd2[k * 32 + j], h2[j]);
    }
    #pragma unroll
    for (int j = 0; j < 32; j++) h2[j] = fmaxf(h2[j], 0.0f);

    // ---- layer 3: out = h2 @ Wd3 + bd3 ----
    float o[32];
    #pragma unroll
    for (int j = 0; j < 32; j++) o[j] = bd3[j];
    #pragma unroll
    for (int k = 0; k < 32; k++) {
        const float c = h2[k];
        #pragma unroll
        for (int j = 0; j < 32; j++)
            o[j] = fmaf(c, Wd3[k * 32 + j], o[j]);
    }

    // ---- coalesced store ----
    float4* o4 = reinterpret_cast<float4*>(out + (size_t)i * 32);
    #pragma unroll
    for (int q = 0; q < 8; q++) {
        float4 v;
        v.x = o[4 * q + 0]; v.y = o[4 * q + 1];
        v.z = o[4 * q + 2]; v.w = o[4 * q + 3];
        o4[q] = v;
    }
}

extern "C" void kernel_launch(void* const* d_in, const int* in_sizes, int n_in,
                              void* d_out, int out_size, void* d_ws, size_t ws_size,
                              hipStream_t stream) {
    // setup_inputs() order:
    //  0 t, 1 zone_embedding, 2 zone_features, 3 person_attrs, 4 edge_index,
    //  5 W1, 6 b1, 7 W2, 8 b2, 9 Wt1, 10 bt1, 11 Wt2, 12 bt2,
    // 13 Wd1, 14 bd1, 15 Wd2, 16 bd2, 17 Wd3, 18 bd3
    const float* t   = (const float*)d_in[0];
    const float* emb = (const float*)d_in[1];
    const float* pa  = (const float*)d_in[3];
    const float* Wt1 = (const float*)d_in[9];
    const float* bt1 = (const float*)d_in[10];
    const float* Wt2 = (const float*)d_in[11];
    const float* bt2 = (const float*)d_in[12];
    const float* Wd1 = (const float*)d_in[13];
    const float* bd1 = (const float*)d_in[14];
    const float* Wd2 = (const float*)d_in[15];
    const float* bd2 = (const float*)d_in[16];
    const float* Wd3 = (const float*)d_in[17];
    const float* bd3 = (const float*)d_in[18];

    const int N = in_sizes[1] / 32;  // 100000
    float* out = (float*)d_out;

    const int blocks = (N + BLK - 1) / BLK;
    zone_velocity_kernel<<<blocks, BLK, 0, stream>>>(
        t, emb, pa, Wt1, bt1, Wt2, bt2,
        Wd1, bd1, Wd2, bd2, Wd3, bd3, out, N);
}